// Round 11
// baseline (553.669 us; speedup 1.0000x reference)
//
#include <hip/hip_runtime.h>

// NeuralIF GraphNet: 3 layers x (lower GraphNet, upper GraphNet).
// R7: one-edge-per-thread edge kernel. 548us.
// R8 FAILED: global A/B tables, original edge order -> 139MB L3 gather.
// R9: bucket-permuted order; 4-array scatter write-amp (160MB) -> 120us.
// R10 FAILED: per-bucket edge blocks w/ 64KB LDS window -> occupancy 20%.
// R11: flat one-edge-per-thread, 256-node buckets, folded Atab. 549us.
// R12 FAILED: fused aggregation via global nsum[row] atomics.
// R14: full row sort + CSR nodemlp + seq per-segment scatter/sort. 508.9us.
// R15: u64 key + split attr. NEUTRAL (513us) -> not stream-BW-bound.
// R16 FAILED-BY-SPILL: 2 edges/thread with default launch bounds: compiler
//      capped VGPR at 48 (occupancy heuristic) and spilled both h[32]
//      accumulators (WRITE_SIZE 4.4->37MB scratch, VALUBusy 63%). The ILP
//      theory was never tested.
// R17: XCD swizzle on nodew/nodemlp (producer-consumer L2 locality). NEUTRAL
//      (515.9us) -> Atab cross-XCD round-trip not dominant, or mapping wrong.
// R18 (this round): retry 2 edges/thread WITH __launch_bounds__(256, 4):
//      grants 512/4 = 128 VGPR budget -> ~110 VGPR state fits, no scratch.
//      16 waves/CU remain (vs 32): acceptable because the 1-edge kernel is
//      ~85% gather-latency-stalled at 13% VALU busy -- we trade idle TLP for
//      2x outstanding gathers/wave + shared uniform weight loads.
//      Watch: VGPR ~96-128 & WRITE_SIZE ~4.4MB = clean test; spill = abort.

typedef unsigned int u32;
typedef unsigned long long u64;

#define NB_SHIFT 8
#define NB_SIZE 256
#define RSTRIDE 1104  // per-GraphNet region: ebins[64] nbins[64*16] pad

__device__ __forceinline__ float wave_sum(float v) {
#pragma unroll
    for (int off = 32; off > 0; off >>= 1) v += __shfl_down(v, off, 64);
    return v;
}

// ---------------- bucketed-list build (once per call) ----------------

__global__ __launch_bounds__(512) void hist_kernel(
    const int* __restrict__ lr, const int* __restrict__ ur,
    u32* __restrict__ hist, int E, int B) {
    __shared__ u32 h[512];
    const int t = threadIdx.x;
    if (t < B) h[t] = 0;
    __syncthreads();
    const int s = blockIdx.y;
    const int* rows = s ? ur : lr;
    for (int i = blockIdx.x * 512 + t; i < E; i += gridDim.x * 512)
        atomicAdd(&h[rows[i] >> NB_SHIFT], 1u);
    __syncthreads();
    if (t < B && h[t]) atomicAdd(&hist[s * B + t], h[t]);
}

// parallel exclusive scan of both segments (B <= 512), one block
__global__ __launch_bounds__(512) void scan_kernel(
    const u32* __restrict__ hist, u32* __restrict__ offs,
    u32* __restrict__ cur, int B) {
    __shared__ u32 sh[512];
    const int t = threadIdx.x;
    for (int s = 0; s < 2; ++s) {
        const u32 v = (t < B) ? hist[s * B + t] : 0u;
        sh[t] = v;
        __syncthreads();
#pragma unroll
        for (int off = 1; off < 512; off <<= 1) {
            const u32 add = (t >= off) ? sh[t - off] : 0u;
            __syncthreads();
            sh[t] += add;
            __syncthreads();
        }
        const u32 exc = sh[t] - v;
        if (t < B) {
            offs[s * (B + 1) + t] = exc;
            cur[s * B + t] = exc;
        }
        if (t == 511) offs[s * (B + 1) + B] = sh[511];
        __syncthreads();
    }
}

// scatter ONE segment: packed bucket-permuted records {row, col, eid, attr}
#define SCHUNK 4096
__global__ __launch_bounds__(512) void scatter_kernel(
    const int* __restrict__ rows, const int* __restrict__ cols,
    const float* __restrict__ attr, u32* __restrict__ cur,
    uint4* __restrict__ my, int E, int B) {
    __shared__ u32 lcnt[512], lbase[512];
    const int t = threadIdx.x;
    if (t < B) lcnt[t] = 0;
    __syncthreads();
    const int base_e = blockIdx.x * SCHUNK;
#pragma unroll
    for (int k = 0; k < SCHUNK / 512; ++k) {
        const int e = base_e + k * 512 + t;
        if (e < E) atomicAdd(&lcnt[rows[e] >> NB_SHIFT], 1u);
    }
    __syncthreads();
    if (t < B) {
        const u32 c = lcnt[t];
        lbase[t] = c ? atomicAdd(&cur[t], c) : 0u;
        lcnt[t] = 0;
    }
    __syncthreads();
#pragma unroll
    for (int k = 0; k < SCHUNK / 512; ++k) {
        const int e = base_e + k * 512 + t;
        if (e < E) {
            const int r = rows[e];
            const int b = r >> NB_SHIFT;
            const u32 pos = lbase[b] + atomicAdd(&lcnt[b], 1u);
            my[pos] = make_uint4((u32)r, (u32)cols[e], (u32)e,
                                 __float_as_uint(attr[e]));
        }
    }
}

// ---- per-bucket LDS counting sort (one segment): bucket -> row order ----
// Emits split arrays: u64 key {eid:21|row:17|col:17} + float attr.
// Also emits per-node CSR offsets (row_offs). One block per bucket.

__global__ __launch_bounds__(512) void sort_kernel(
    const uint4* __restrict__ in, u64* __restrict__ okey,
    float* __restrict__ oattr, const u32* __restrict__ offs,
    u32* __restrict__ row_offs, int E, int N) {
    __shared__ u32 cnt[NB_SIZE];
    __shared__ u32 scn[NB_SIZE];
    const int t = threadIdx.x;
    const int b = blockIdx.x;
    const u32 beg = offs[b], end = offs[b + 1];
    if (t < NB_SIZE) cnt[t] = 0;
    __syncthreads();
    for (u32 i = beg + t; i < end; i += 512)
        atomicAdd(&cnt[in[i].x & (NB_SIZE - 1)], 1u);
    __syncthreads();
    if (t < NB_SIZE) scn[t] = cnt[t];
    __syncthreads();
#pragma unroll
    for (int off = 1; off < NB_SIZE; off <<= 1) {
        u32 add = 0;
        if (t < NB_SIZE && t >= off) add = scn[t - off];
        __syncthreads();
        if (t < NB_SIZE) scn[t] += add;
        __syncthreads();
    }
    const int n0 = b << NB_SHIFT;
    if (t < NB_SIZE) {
        const u32 excl = scn[t] - cnt[t];
        if (n0 + t < N) row_offs[n0 + t] = beg + excl;
        cnt[t] = excl;  // reuse as write cursor
    }
    if (b == 0 && t == 0) row_offs[N] = (u32)E;
    __syncthreads();
    for (u32 i = beg + t; i < end; i += 512) {
        const uint4 r = in[i];
        const u32 pos = beg + atomicAdd(&cnt[r.x & (NB_SIZE - 1)], 1u);
        okey[pos] = ((u64)r.z << 34) | ((u64)(r.x & 0x1FFFFu) << 17) |
                    (u64)(r.y & 0x1FFFFu);
        oattr[pos] = __uint_as_float(r.w);
    }
}

// -------- per-node A-table with g+bias fold (and the g-MLP itself) --------
// Atab[n][j] = b1[j] + sum_k g[k]*W1[k,j] + sum_k x[n,k]*W1[8+k,j]
// XCD-chunked block swizzle aligns the writer XCD of Atab[n] with the edge
// kernel's reader XCD (row-sorted edges -> XCD x reads rows ~[x*N/8..)).

template <bool GCOMP>
__global__ __launch_bounds__(256) void nodew_kernel(
    const float4* __restrict__ xf, const float* __restrict__ W1,
    const float* __restrict__ b1,
    const float* __restrict__ gprev,   // gslot[j-1] (or gslot[0]=0)
    float* __restrict__ gout,          // gslot[j] (GCOMP: block0 writes)
    const float* __restrict__ pebins,  // prev region e-mean bins (GCOMP)
    const float* __restrict__ pnbins,  // prev region n-mean bins (GCOMP)
    const float* __restrict__ gW1, const float* __restrict__ gb1,
    const float* __restrict__ gW2, const float* __restrict__ gb2,
    float4* __restrict__ Atab, int N, float inv_E, int cpn) {
    __shared__ float gsh[8];
    const int t = threadIdx.x;
    if constexpr (GCOMP) {
        if (t < 64) {  // wave 0: g = gMLP(n_mean, e_mean, g_prev)
            float nb[8];
#pragma unroll
            for (int q = 0; q < 8; ++q) nb[q] = pnbins[t * 16 + q];
            const float eb = pebins[t];
            float gin[17];
#pragma unroll
            for (int q = 0; q < 8; ++q) {
                const float s = wave_sum(nb[q]);
                gin[q] = __shfl(s, 0, 64) / (float)N;
            }
            const float es = wave_sum(eb);
            gin[8] = __shfl(es, 0, 64) * inv_E;
#pragma unroll
            for (int k = 0; k < 8; ++k) gin[9 + k] = gprev[k];
            float hv = 0.0f;
            if (t < 32) {
                hv = gb1[t];
#pragma unroll
                for (int k = 0; k < 17; ++k)
                    hv = fmaf(gin[k], gW1[k * 32 + t], hv);
                hv = fmaxf(hv, 0.0f);
            }
#pragma unroll
            for (int q = 0; q < 8; ++q) {
                const float c = (t < 32) ? hv * gW2[t * 8 + q] : 0.0f;
                const float s = wave_sum(c);
                if (t == 0) {
                    const float gv = gb2[q] + s;
                    gsh[q] = gv;
                    if (blockIdx.x == 0) gout[q] = gv;
                }
            }
        }
    } else {
        if (t < 8) gsh[t] = gprev[t];  // zeros for GraphNet 0
    }
    __syncthreads();
    const int lid = (blockIdx.x & 7) * cpn + (blockIdx.x >> 3);
    const int n = lid * 256 + t;
    if (n >= N) return;
    float gr[8];
#pragma unroll
    for (int k = 0; k < 8; ++k) gr[k] = gsh[k];
    const float4 x0 = xf[2 * (size_t)n], x1 = xf[2 * (size_t)n + 1];
    const float xs[8] = {x0.x, x0.y, x0.z, x0.w, x1.x, x1.y, x1.z, x1.w};
    float a[32];
#pragma unroll
    for (int j = 0; j < 32; ++j) {
        float v = b1[j];
#pragma unroll
        for (int k = 0; k < 8; ++k) v = fmaf(gr[k], W1[k * 32 + j], v);
        a[j] = v;
    }
    const float* __restrict__ WA = W1 + 8 * 32;
#pragma unroll
    for (int k = 0; k < 8; ++k) {
        const float v = xs[k];
#pragma unroll
        for (int j = 0; j < 32; ++j) a[j] = fmaf(v, WA[k * 32 + j], a[j]);
    }
    float4* An = Atab + 8 * (size_t)n;
#pragma unroll
    for (int q = 0; q < 8; ++q)
        An[q] = make_float4(a[4 * q], a[4 * q + 1], a[4 * q + 2], a[4 * q + 3]);
}

// ---------------- edge MLP: flat grid, TWO edges per thread ----------------
// __launch_bounds__(256, 4) -> 128-VGPR budget: h[32]+g2[32] state fits
// without scratch (R16's spill). Thread t handles i0+t and i0+256+t (both
// coalesced); 2x independent gathers per wave; uniform weight loads shared.

template <bool SKIP, bool FIRST, bool GAGG, bool VALS, bool STORE>
__global__ __launch_bounds__(256, 4) void edge_kernel(
    const u64* __restrict__ ekey,      // packed row-sorted keys
    const float* __restrict__ eattr,   // permuted original attrs
    const float4* __restrict__ Atab,   // folded per-node partials
    const float4* __restrict__ xf,     // current node features (x or l_n)
    const float* __restrict__ eprev,   // prev edge emb (permuted), !FIRST
    const float* __restrict__ W1,      // 26x32 slice (row-major k,j)
    const float* __restrict__ W2,      // 32
    const float* __restrict__ b2,      // 1
    float* __restrict__ ebins,         // this region's e-mean bins (GAGG)
    float* __restrict__ e_out,         // edge emb store (permuted, STORE)
    float* __restrict__ vals_out,      // final output segment (VALS)
    int E, int cpx) {
    __shared__ float wpart[4];
    const int t = threadIdx.x;
    const int lid = (blockIdx.x & 7) * cpx + (blockIdx.x >> 3);
    const int i0 = lid * 512;
    if (i0 >= E) return;  // padded-grid tail block
    const int ia = i0 + t;
    const int ib = i0 + 256 + t;
    const bool va = ia < E;
    const bool vb = ib < E;
    const int xa = va ? ia : i0;
    const int xb = vb ? ib : i0;

    // --- issue both edges' loads up front ---
    const u64 ka = ekey[xa];
    const u64 kb = ekey[xb];
    const u32 ca = (u32)ka & 0x1FFFFu, ra = (u32)(ka >> 17) & 0x1FFFFu;
    const u32 cb = (u32)kb & 0x1FFFFu, rb = (u32)(kb >> 17) & 0x1FFFFu;
    float attra = 0.0f, attrb = 0.0f;
    if constexpr (FIRST || SKIP) { attra = eattr[xa]; attrb = eattr[xb]; }
    float epa, epb;
    if constexpr (FIRST) { epa = attra; epb = attrb; }
    else { epa = eprev[xa]; epb = eprev[xb]; }
    const float4* __restrict__ Ara = Atab + 8 * (size_t)ra;
    const float4* __restrict__ Arb = Atab + 8 * (size_t)rb;
    float h[32], g2[32];
#pragma unroll
    for (int q = 0; q < 8; ++q) {
        const float4 av = Ara[q];
        h[4 * q + 0] = av.x; h[4 * q + 1] = av.y;
        h[4 * q + 2] = av.z; h[4 * q + 3] = av.w;
        const float4 bv = Arb[q];
        g2[4 * q + 0] = bv.x; g2[4 * q + 1] = bv.y;
        g2[4 * q + 2] = bv.z; g2[4 * q + 3] = bv.w;
    }
    const float4 xa0 = xf[2 * (size_t)ca], xa1 = xf[2 * (size_t)ca + 1];
    const float4 xb0 = xf[2 * (size_t)cb], xb1 = xf[2 * (size_t)cb + 1];
    const float cxa[8] = {xa0.x, xa0.y, xa0.z, xa0.w,
                          xa1.x, xa1.y, xa1.z, xa1.w};
    const float cxb[8] = {xb0.x, xb0.y, xb0.z, xb0.w,
                          xb1.x, xb1.y, xb1.z, xb1.w};
    // --- shared-weight dual compute ---
    const float* __restrict__ Wc = W1 + 16 * 32;  // col rows 16..23
#pragma unroll
    for (int k = 0; k < 8; ++k) {
        const float va_ = cxa[k];
        const float vb_ = cxb[k];
#pragma unroll
        for (int j = 0; j < 32; ++j) {
            const float w = Wc[k * 32 + j];
            h[j] = fmaf(va_, w, h[j]);
            g2[j] = fmaf(vb_, w, g2[j]);
        }
    }
    const float* __restrict__ W24 = W1 + 24 * 32;
#pragma unroll
    for (int j = 0; j < 32; ++j) {
        const float w = W24[j];
        h[j] = fmaf(epa, w, h[j]);
        g2[j] = fmaf(epb, w, g2[j]);
    }
    if constexpr (SKIP) {
        const float* __restrict__ W25 = W1 + 25 * 32;
#pragma unroll
        for (int j = 0; j < 32; ++j) {
            const float w = W25[j];
            h[j] = fmaf(attra, w, h[j]);
            g2[j] = fmaf(attrb, w, g2[j]);
        }
    }
    float outa = b2[0], outb = b2[0];
#pragma unroll
    for (int j = 0; j < 32; ++j) {
        const float w = W2[j];
        outa = fmaf(fmaxf(h[j], 0.0f), w, outa);
        outb = fmaf(fmaxf(g2[j], 0.0f), w, outb);
    }

    if (va) {
        if constexpr (STORE) e_out[ia] = outa;
        if constexpr (VALS) {
            const u32 eid = (u32)(ka >> 34);
            vals_out[eid] = (ra == ca) ? expf(outa) : outa;
        }
    }
    if (vb) {
        if constexpr (STORE) e_out[ib] = outb;
        if constexpr (VALS) {
            const u32 eid = (u32)(kb >> 34);
            vals_out[eid] = (rb == cb) ? expf(outb) : outb;
        }
    }
    if constexpr (GAGG) {
        const float s =
            wave_sum((va ? outa : 0.0f) + (vb ? outb : 0.0f));
        if ((t & 63) == 0) wpart[t >> 6] = s;
        __syncthreads();
        if (t == 0)
            atomicAdd(&ebins[lid & 63],
                      wpart[0] + wpart[1] + wpart[2] + wpart[3]);
    }
}

// -- slim per-node MLP: CSR segment sum (contiguous, no atomics) + MLP --
// XCD-chunked swizzle aligns e_out reads with the edge kernel's writer XCD.

template <bool STORE_N>
__global__ __launch_bounds__(256) void nodemlp_kernel(
    const float* __restrict__ ep,      // row-sorted edge embeddings
    const u32* __restrict__ row_offs,  // N+1 CSR offsets
    const float4* __restrict__ xf,   // node features: x (lower) or l_n (upper)
    const float* __restrict__ g,     // gslot[j] (materialized)
    const float* __restrict__ nW1, const float* __restrict__ nb1,
    const float* __restrict__ nW2, const float* __restrict__ nb2,
    float* __restrict__ n_out,  // l_n (8N) if STORE_N
    float* __restrict__ nbins,  // 64 x 16 n-mean partial bins
    int N, int cpn) {
    __shared__ float biasN[32];
    __shared__ float npart[4][8];
    const int t = threadIdx.x;
    if (t < 32) {
        float v = nb1[t];
#pragma unroll
        for (int k = 0; k < 8; ++k) v = fmaf(g[k], nW1[k * 32 + t], v);
        biasN[t] = v;
    }
    __syncthreads();
    const int lid = (blockIdx.x & 7) * cpn + (blockIdx.x >> 3);
    const int n = lid * 256 + t;
    const bool active = n < N;
    const int idx = active ? n : (N - 1);
    const u32 beg = row_offs[idx], end = row_offs[idx + 1];
    float ssum = 0.0f;
    for (u32 i = beg; i < end; ++i) ssum += ep[i];
    const float agg = ssum / fmaxf((float)(end - beg), 1.0f);
    const float4 x0 = xf[2 * (size_t)idx], x1 = xf[2 * (size_t)idx + 1];
    float in[9] = {x0.x, x0.y, x0.z, x0.w, x1.x, x1.y, x1.z, x1.w, agg};
    float h[32];
#pragma unroll
    for (int j = 0; j < 8; ++j) {
        const float4 bb = reinterpret_cast<const float4*>(biasN)[j];
        h[4 * j + 0] = bb.x; h[4 * j + 1] = bb.y;
        h[4 * j + 2] = bb.z; h[4 * j + 3] = bb.w;
    }
    const float* __restrict__ Wk = nW1 + 8 * 32;
#pragma unroll
    for (int k = 0; k < 9; ++k) {
        const float v = in[k];
#pragma unroll
        for (int j = 0; j < 32; ++j) h[j] = fmaf(v, Wk[k * 32 + j], h[j]);
    }
    float o[8];
#pragma unroll
    for (int q = 0; q < 8; ++q) o[q] = nb2[q];
#pragma unroll
    for (int j = 0; j < 32; ++j) {
        const float hv = fmaxf(h[j], 0.0f);
#pragma unroll
        for (int q = 0; q < 8; ++q) o[q] = fmaf(hv, nW2[j * 8 + q], o[q]);
    }
    if constexpr (STORE_N) {
        if (active) {
            reinterpret_cast<float4*>(n_out)[2 * n] =
                make_float4(o[0], o[1], o[2], o[3]);
            reinterpret_cast<float4*>(n_out)[2 * n + 1] =
                make_float4(o[4], o[5], o[6], o[7]);
        }
    }
#pragma unroll
    for (int q = 0; q < 8; ++q) {
        const float s2 = wave_sum(active ? o[q] : 0.0f);
        if ((t & 63) == 0) npart[t >> 6][q] = s2;
    }
    __syncthreads();
    if (t < 8) {
        float a = 0.0f;
#pragma unroll
        for (int w = 0; w < 4; ++w) a += npart[w][t];
        atomicAdd(&nbins[(blockIdx.x & 63) * 16 + t], a);
    }
}

extern "C" void kernel_launch(void* const* d_in, const int* in_sizes, int n_in,
                              void* d_out, int out_size, void* d_ws,
                              size_t ws_size, hipStream_t stream) {
    const float* x = (const float*)d_in[0];
    const int* l_ei = (const int*)d_in[1];
    const int* u_ei = (const int*)d_in[2];
    const float* l_attr = (const float*)d_in[3];
    const float* u_attr = (const float*)d_in[4];
    const float* eW1 = (const float*)d_in[5];
    const float* eb1 = (const float*)d_in[6];
    const float* eW2 = (const float*)d_in[7];
    const float* eb2 = (const float*)d_in[8];
    const float* nW1 = (const float*)d_in[9];
    const float* nb1 = (const float*)d_in[10];
    const float* nW2 = (const float*)d_in[11];
    const float* nb2 = (const float*)d_in[12];
    const float* gW1 = (const float*)d_in[13];
    const float* gb1 = (const float*)d_in[14];
    const float* gW2 = (const float*)d_in[15];
    const float* gb2 = (const float*)d_in[16];

    const int E = in_sizes[3];      // 1,100,000
    const int N = in_sizes[0] / 8;  // 100,000
    const int B = (N + NB_SIZE - 1) >> NB_SHIFT;  // 391 buckets
    const int Ep = (E + 3) & ~3;    // float4-safe stride for emb arrays

    // workspace layout (~52.5MB):
    //  [ekeys 2E u64][eattrs 2E f32]
    //  [tmp (bucket order, E uint4; dead after sorts) -> Atab + l_e alias]
    //  [u_e][l_n][gslot|hist|dyn|offs|cur|row_offs]
    u64* ekeys = (u64*)d_ws;                       // 2E keys
    float* eattrs = (float*)(ekeys + (size_t)2 * E);  // 2E attrs
    uint4* tmp = (uint4*)(eattrs + (size_t)2 * E); // E tmp records
    float* Atab = (float*)tmp;                     // alias (post-sort)
    float* l_e = Atab + (size_t)32 * N;            // Ep (alias, fits in tmp)
    float* u_e = (float*)(tmp + (size_t)E);        // Ep
    float* l_n = u_e + Ep;                         // 8N
    float* gslot = l_n + (size_t)8 * N;            // 7 x 8
    u32* hist = (u32*)(gslot + 56);                // 2B
    float* dyn_all = (float*)(hist + 2 * B);       // 5 * RSTRIDE
    u32* offs = (u32*)(dyn_all + 5 * RSTRIDE);     // 2(B+1)
    u32* cur = offs + 2 * (B + 1);                 // 2B
    u32* row_offs = cur + 2 * B;                   // 2(N+1) CSR offsets

    const int* lr = l_ei;
    const int* lc = l_ei + E;
    const int* ur = u_ei;
    const int* uc = u_ei + E;
    const int sg = (E + SCHUNK - 1) / SCHUNK;
    const int ng = (N + 255) / 256;
    const int ngp = (ng + 7) & ~7;   // padded node grid (%8) for XCD swizzle
    const int cpn = ngp >> 3;
    const int eg2 = (E + 511) / 512;  // 2 edges/thread
    const int nwg8 = (eg2 + 7) & ~7;  // padded edge grid (%8)
    const int cpx = nwg8 >> 3;
    const float invE = 1.0f / (float)E;
    float* outL = (float*)d_out;
    float* outU = outL + E;

    // one memset: gslots + hist + all 5 bin regions
    hipMemsetAsync(gslot, 0, (size_t)(56 + 2 * B + 5 * RSTRIDE) * sizeof(float),
                   stream);
    hist_kernel<<<dim3(64, 2), 512, 0, stream>>>(lr, ur, hist, E, B);
    scan_kernel<<<1, 512, 0, stream>>>(hist, offs, cur, B);
    // per-segment scatter+sort, sequential (tmp holds ONE segment at a time)
    scatter_kernel<<<sg, 512, 0, stream>>>(lr, lc, l_attr, cur, tmp, E, B);
    sort_kernel<<<B, 512, 0, stream>>>(tmp, ekeys, eattrs, offs, row_offs,
                                       E, N);
    scatter_kernel<<<sg, 512, 0, stream>>>(ur, uc, u_attr, cur + B, tmp, E, B);
    sort_kernel<<<B, 512, 0, stream>>>(tmp, ekeys + (size_t)E,
                                       eattrs + (size_t)E, offs + (B + 1),
                                       row_offs + (N + 1), E, N);

    // weight-slice per GraphNet j: lower i -> i, upper i -> 3+i
    const size_t wsl[6] = {0, 3, 1, 4, 2, 5};

    for (int j = 0; j < 6; ++j) {
        const bool lower = !(j & 1);
        const size_t sl = wsl[j];
        float* ebins = dyn_all + (size_t)(j <= 4 ? j : 4) * RSTRIDE;
        float* nbins = ebins + 64;
        const float* pe = (j >= 1) ? dyn_all + (size_t)(j - 1) * RSTRIDE : nullptr;
        const float* pn = (j >= 1) ? pe + 64 : nullptr;
        const size_t psl = (j >= 1) ? wsl[j - 1] : 0;
        const float4* exf = (const float4*)(lower ? x : l_n);
        const u64* ekey_t = ekeys + (size_t)(lower ? 0 : 1) * E;
        const float* eattr_t = eattrs + (size_t)(lower ? 0 : 1) * E;
        const u32* roffs = row_offs + (size_t)(lower ? 0 : 1) * (N + 1);
        const float* eprev = lower ? l_e : u_e;  // unused when FIRST
        float* e_out = lower ? l_e : u_e;
        const float* gprev = gslot + (size_t)(j >= 1 ? j - 1 : 0) * 8;
        float* gout = gslot + (size_t)j * 8;

        // folded per-node A-table (+ g-MLP; block0 materializes gslot[j])
        if (j == 0)
            nodew_kernel<false><<<ngp, 256, 0, stream>>>(
                exf, eW1 + sl * 832, eb1 + sl * 32, gprev, gout, pe, pn,
                gW1, gb1, gW2, gb2, (float4*)Atab, N, invE, cpn);
        else
            nodew_kernel<true><<<ngp, 256, 0, stream>>>(
                exf, eW1 + sl * 832, eb1 + sl * 32, gprev, gout, pe, pn,
                gW1 + psl * 544, gb1 + psl * 32, gW2 + psl * 256,
                gb2 + psl * 8, (float4*)Atab, N, invE, cpn);

#define EDGE_ARGS                                                             \
    ekey_t, eattr_t, (const float4*)Atab, exf, eprev, eW1 + sl * 832,         \
        eW2 + sl * 32, eb2 + sl, ebins, e_out, (j == 4) ? outL : outU, E, cpx

        switch (j) {  // SKIP, FIRST, GAGG, VALS, STORE
            case 0: edge_kernel<false, true, true, false, true>
                        <<<nwg8, 256, 0, stream>>>(EDGE_ARGS); break;
            case 1: edge_kernel<false, true, true, false, true>
                        <<<nwg8, 256, 0, stream>>>(EDGE_ARGS); break;
            case 2: edge_kernel<true, false, true, false, true>
                        <<<nwg8, 256, 0, stream>>>(EDGE_ARGS); break;
            case 3: edge_kernel<false, false, true, false, true>
                        <<<nwg8, 256, 0, stream>>>(EDGE_ARGS); break;
            case 4: edge_kernel<true, false, true, true, true>
                        <<<nwg8, 256, 0, stream>>>(EDGE_ARGS); break;
            case 5: edge_kernel<false, false, false, true, false>
                        <<<nwg8, 256, 0, stream>>>(EDGE_ARGS); break;
        }
#undef EDGE_ARGS

        if (j == 5) break;  // final upper GraphNet: edge output only

        const float4* nxf = (const float4*)(lower ? x : l_n);

#define NODE_ARGS                                                             \
    e_out, roffs, nxf, gslot + (size_t)j * 8, nW1 + sl * 544, nb1 + sl * 32,  \
        nW2 + sl * 256, nb2 + sl * 8, l_n, nbins, N, cpn

        switch (j) {  // STORE_N
            case 0: nodemlp_kernel<true>
                        <<<ngp, 256, 0, stream>>>(NODE_ARGS); break;
            case 1: nodemlp_kernel<false>
                        <<<ngp, 256, 0, stream>>>(NODE_ARGS); break;
            case 2: nodemlp_kernel<true>
                        <<<ngp, 256, 0, stream>>>(NODE_ARGS); break;
            case 3: nodemlp_kernel<false>
                        <<<ngp, 256, 0, stream>>>(NODE_ARGS); break;
            case 4: nodemlp_kernel<true>
                        <<<ngp, 256, 0, stream>>>(NODE_ARGS); break;
        }
#undef NODE_ARGS
    }
}

// Round 12
// 503.629 us; speedup vs baseline: 1.0994x; 1.0994x over previous
//
#include <hip/hip_runtime.h>

// NeuralIF GraphNet: 3 layers x (lower GraphNet, upper GraphNet).
// R7: one-edge-per-thread edge kernel. 548us.
// R8 FAILED: global A/B tables, original edge order -> 139MB L3 gather.
// R9: bucket-permuted order; scatter write-amp -> 120us.
// R10 FAILED: per-bucket edge blocks w/ 64KB LDS window -> occupancy 20%.
// R11: flat one-edge-per-thread, 256-node buckets, folded Atab. 549us.
// R12 FAILED: fused aggregation via global nsum[row] atomics.
// R14: full row sort + CSR nodemlp + seq per-segment scatter/sort. 508.9us.
// R15: u64 key + split attr. NEUTRAL (513us) -> not stream-BW-bound.
// R16/R18 FAILED-BY-SPILL x2: 2 edges/thread spills h[32] pair regardless of
//      __launch_bounds__ (regalloc heuristic picks 48 VGPR + scratch;
//      launch_bounds only caps, never raises). ILP path abandoned.
// R17: XCD swizzle on nodew/nodemlp. NEUTRAL.
// R19 (this round): dispatch elimination. Edge kernel reverted to R15's
//      1-edge shape + the R10-R13-proven inline GCOMP/biasE fold (g moves
//      OUT of Atab into per-block LDS bias). Atab is then g-independent:
//      - atabx_kernel precomputes ALL THREE lower Atabs once (x is static).
//      - even-j nodemlp fuses the upper Atab write (l_n already in regs).
//      Kills all 6 nodew dispatches (~60us with gaps) for +1 upfront kernel.

typedef unsigned int u32;
typedef unsigned long long u64;

#define NB_SHIFT 8
#define NB_SIZE 256
#define RSTRIDE 1104  // per-GraphNet region: ebins[64] nbins[64*16] pad

__device__ __forceinline__ float wave_sum(float v) {
#pragma unroll
    for (int off = 32; off > 0; off >>= 1) v += __shfl_down(v, off, 64);
    return v;
}

// ---------------- bucketed-list build (once per call) ----------------

__global__ __launch_bounds__(512) void hist_kernel(
    const int* __restrict__ lr, const int* __restrict__ ur,
    u32* __restrict__ hist, int E, int B) {
    __shared__ u32 h[512];
    const int t = threadIdx.x;
    if (t < B) h[t] = 0;
    __syncthreads();
    const int s = blockIdx.y;
    const int* rows = s ? ur : lr;
    for (int i = blockIdx.x * 512 + t; i < E; i += gridDim.x * 512)
        atomicAdd(&h[rows[i] >> NB_SHIFT], 1u);
    __syncthreads();
    if (t < B && h[t]) atomicAdd(&hist[s * B + t], h[t]);
}

// parallel exclusive scan of both segments (B <= 512), one block
__global__ __launch_bounds__(512) void scan_kernel(
    const u32* __restrict__ hist, u32* __restrict__ offs,
    u32* __restrict__ cur, int B) {
    __shared__ u32 sh[512];
    const int t = threadIdx.x;
    for (int s = 0; s < 2; ++s) {
        const u32 v = (t < B) ? hist[s * B + t] : 0u;
        sh[t] = v;
        __syncthreads();
#pragma unroll
        for (int off = 1; off < 512; off <<= 1) {
            const u32 add = (t >= off) ? sh[t - off] : 0u;
            __syncthreads();
            sh[t] += add;
            __syncthreads();
        }
        const u32 exc = sh[t] - v;
        if (t < B) {
            offs[s * (B + 1) + t] = exc;
            cur[s * B + t] = exc;
        }
        if (t == 511) offs[s * (B + 1) + B] = sh[511];
        __syncthreads();
    }
}

// scatter ONE segment: packed bucket-permuted records {row, col, eid, attr}
#define SCHUNK 4096
__global__ __launch_bounds__(512) void scatter_kernel(
    const int* __restrict__ rows, const int* __restrict__ cols,
    const float* __restrict__ attr, u32* __restrict__ cur,
    uint4* __restrict__ my, int E, int B) {
    __shared__ u32 lcnt[512], lbase[512];
    const int t = threadIdx.x;
    if (t < B) lcnt[t] = 0;
    __syncthreads();
    const int base_e = blockIdx.x * SCHUNK;
#pragma unroll
    for (int k = 0; k < SCHUNK / 512; ++k) {
        const int e = base_e + k * 512 + t;
        if (e < E) atomicAdd(&lcnt[rows[e] >> NB_SHIFT], 1u);
    }
    __syncthreads();
    if (t < B) {
        const u32 c = lcnt[t];
        lbase[t] = c ? atomicAdd(&cur[t], c) : 0u;
        lcnt[t] = 0;
    }
    __syncthreads();
#pragma unroll
    for (int k = 0; k < SCHUNK / 512; ++k) {
        const int e = base_e + k * 512 + t;
        if (e < E) {
            const int r = rows[e];
            const int b = r >> NB_SHIFT;
            const u32 pos = lbase[b] + atomicAdd(&lcnt[b], 1u);
            my[pos] = make_uint4((u32)r, (u32)cols[e], (u32)e,
                                 __float_as_uint(attr[e]));
        }
    }
}

// ---- per-bucket LDS counting sort (one segment): bucket -> row order ----
// Emits split arrays: u64 key {eid:21|row:17|col:17} + float attr.
// Also emits per-node CSR offsets (row_offs). One block per bucket.

__global__ __launch_bounds__(512) void sort_kernel(
    const uint4* __restrict__ in, u64* __restrict__ okey,
    float* __restrict__ oattr, const u32* __restrict__ offs,
    u32* __restrict__ row_offs, int E, int N) {
    __shared__ u32 cnt[NB_SIZE];
    __shared__ u32 scn[NB_SIZE];
    const int t = threadIdx.x;
    const int b = blockIdx.x;
    const u32 beg = offs[b], end = offs[b + 1];
    if (t < NB_SIZE) cnt[t] = 0;
    __syncthreads();
    for (u32 i = beg + t; i < end; i += 512)
        atomicAdd(&cnt[in[i].x & (NB_SIZE - 1)], 1u);
    __syncthreads();
    if (t < NB_SIZE) scn[t] = cnt[t];
    __syncthreads();
#pragma unroll
    for (int off = 1; off < NB_SIZE; off <<= 1) {
        u32 add = 0;
        if (t < NB_SIZE && t >= off) add = scn[t - off];
        __syncthreads();
        if (t < NB_SIZE) scn[t] += add;
        __syncthreads();
    }
    const int n0 = b << NB_SHIFT;
    if (t < NB_SIZE) {
        const u32 excl = scn[t] - cnt[t];
        if (n0 + t < N) row_offs[n0 + t] = beg + excl;
        cnt[t] = excl;  // reuse as write cursor
    }
    if (b == 0 && t == 0) row_offs[N] = (u32)E;
    __syncthreads();
    for (u32 i = beg + t; i < end; i += 512) {
        const uint4 r = in[i];
        const u32 pos = beg + atomicAdd(&cnt[r.x & (NB_SIZE - 1)], 1u);
        okey[pos] = ((u64)r.z << 34) | ((u64)(r.x & 0x1FFFFu) << 17) |
                    (u64)(r.y & 0x1FFFFu);
        oattr[pos] = __uint_as_float(r.w);
    }
}

// ---- upfront: all 3 lower A-tables from static x (g-independent) ----
// AtabL[m][n][j] = sum_k x[n,k] * W1_m[(8+k)*32+j], m = lower slice 0,1,2

__global__ __launch_bounds__(256) void atabx_kernel(
    const float4* __restrict__ xf, const float* __restrict__ eW1,
    float4* __restrict__ AtabL, int N) {
    const int n = blockIdx.x * 256 + threadIdx.x;
    if (n >= N) return;
    const float4 x0 = xf[2 * (size_t)n], x1 = xf[2 * (size_t)n + 1];
    const float xs[8] = {x0.x, x0.y, x0.z, x0.w, x1.x, x1.y, x1.z, x1.w};
    for (int m = 0; m < 3; ++m) {
        const float* __restrict__ WA = eW1 + (size_t)m * 832 + 8 * 32;
        float a[32];
#pragma unroll
        for (int j = 0; j < 32; ++j) a[j] = 0.0f;
#pragma unroll
        for (int k = 0; k < 8; ++k) {
            const float v = xs[k];
#pragma unroll
            for (int j = 0; j < 32; ++j) a[j] = fmaf(v, WA[k * 32 + j], a[j]);
        }
        float4* An = AtabL + (size_t)m * 8 * N + 8 * (size_t)n;
#pragma unroll
        for (int q = 0; q < 8; ++q)
            An[q] = make_float4(a[4 * q], a[4 * q + 1], a[4 * q + 2],
                                a[4 * q + 3]);
    }
}

// ---------------- edge MLP: flat grid, one edge per thread ----------------
// GCOMP (wave 0) computes g inline from prev bins; t<32 folds b1 + g.W1[0:8]
// into LDS biasE (R10-R13-proven). Atab rows carry only x.W1[8:16].
// Row-sorted order keeps A-row gathers L1-broadcast; XCD-chunked swizzle.

template <bool SKIP, bool FIRST, bool GAGG, bool VALS, bool STORE, bool GCOMP>
__global__ __launch_bounds__(256) void edge_kernel(
    const u64* __restrict__ ekey,      // packed row-sorted keys
    const float* __restrict__ eattr,   // permuted original attrs
    const float4* __restrict__ Atab,   // per-node x.W1[8:16] partials
    const float4* __restrict__ xf,     // current node features (x or l_n)
    const float* __restrict__ eprev,   // prev edge emb (permuted), !FIRST
    const float* __restrict__ W1,      // 26x32 slice (row-major k,j)
    const float* __restrict__ b1,      // 32
    const float* __restrict__ W2,      // 32
    const float* __restrict__ b2,      // 1
    const float* __restrict__ gprev,   // gslot[j-1] (or gslot[0]=0)
    float* __restrict__ gout,          // gslot[j] (GCOMP: block0 writes)
    const float* __restrict__ pebins,  // prev region e-mean bins (GCOMP)
    const float* __restrict__ pnbins,  // prev region n-mean bins (GCOMP)
    const float* __restrict__ gW1, const float* __restrict__ gb1,
    const float* __restrict__ gW2, const float* __restrict__ gb2,
    float* __restrict__ ebins,         // this region's e-mean bins (GAGG)
    float* __restrict__ e_out,         // edge emb store (permuted, STORE)
    float* __restrict__ vals_out,      // final output segment (VALS)
    int E, int N, float inv_E, int cpx) {
    __shared__ float gsh[8];
    __shared__ float biasE[32];
    __shared__ float wpart[4];
    const int t = threadIdx.x;
    const int lid = (blockIdx.x & 7) * cpx + (blockIdx.x >> 3);
    const int i0 = lid * 256;
    if (i0 >= E) return;  // padded-grid tail block (uniform exit)

    if constexpr (GCOMP) {
        if (t < 64) {  // wave 0: g = gMLP(n_mean, e_mean, g_prev)
            float nb[8];
#pragma unroll
            for (int q = 0; q < 8; ++q) nb[q] = pnbins[t * 16 + q];
            const float eb = pebins[t];
            float gin[17];
#pragma unroll
            for (int q = 0; q < 8; ++q) {
                const float s = wave_sum(nb[q]);
                gin[q] = __shfl(s, 0, 64) / (float)N;
            }
            const float es = wave_sum(eb);
            gin[8] = __shfl(es, 0, 64) * inv_E;
#pragma unroll
            for (int k = 0; k < 8; ++k) gin[9 + k] = gprev[k];
            float hv = 0.0f;
            if (t < 32) {
                hv = gb1[t];
#pragma unroll
                for (int k = 0; k < 17; ++k)
                    hv = fmaf(gin[k], gW1[k * 32 + t], hv);
                hv = fmaxf(hv, 0.0f);
            }
#pragma unroll
            for (int q = 0; q < 8; ++q) {
                const float c = (t < 32) ? hv * gW2[t * 8 + q] : 0.0f;
                const float s = wave_sum(c);
                if (t == 0) {
                    const float gv = gb2[q] + s;
                    gsh[q] = gv;
                    if (blockIdx.x == 0) gout[q] = gv;
                }
            }
        }
    } else {
        if (t < 8) gsh[t] = gprev[t];  // zeros for GraphNet 0
    }
    __syncthreads();
    if (t < 32) {  // fold uniform global contribution + b1 into bias
        float v = b1[t];
#pragma unroll
        for (int k = 0; k < 8; ++k) v = fmaf(gsh[k], W1[k * 32 + t], v);
        biasE[t] = v;
    }
    __syncthreads();

    const int i = i0 + t;
    const bool valid = i < E;
    const int idx = valid ? i : i0;

    const u64 key = ekey[idx];
    const u32 c = (u32)key & 0x1FFFFu;
    const u32 r = (u32)(key >> 17) & 0x1FFFFu;
    float attr = 0.0f;
    if constexpr (FIRST || SKIP) attr = eattr[idx];
    float epv;
    if constexpr (FIRST) epv = attr;
    else epv = eprev[idx];
    // A-row gather (8x16B; consecutive lanes share rows -> broadcast)
    const float4* __restrict__ Ar = Atab + 8 * (size_t)r;
    float h[32];
#pragma unroll
    for (int q = 0; q < 8; ++q) {
        const float4 av = Ar[q];
        const float4 bi = reinterpret_cast<const float4*>(biasE)[q];
        h[4 * q + 0] = bi.x + av.x; h[4 * q + 1] = bi.y + av.y;
        h[4 * q + 2] = bi.z + av.z; h[4 * q + 3] = bi.w + av.w;
    }
    // col features (32B gather, L2-resident table)
    const float4 xc0 = xf[2 * (size_t)c], xc1 = xf[2 * (size_t)c + 1];
    const float cx[8] = {xc0.x, xc0.y, xc0.z, xc0.w,
                         xc1.x, xc1.y, xc1.z, xc1.w};
    const float* __restrict__ Wc = W1 + 16 * 32;  // col rows 16..23
#pragma unroll
    for (int k = 0; k < 8; ++k) {
        const float v = cx[k];
#pragma unroll
        for (int j = 0; j < 32; ++j) h[j] = fmaf(v, Wc[k * 32 + j], h[j]);
    }
    const float* __restrict__ W24 = W1 + 24 * 32;
#pragma unroll
    for (int j = 0; j < 32; ++j) h[j] = fmaf(epv, W24[j], h[j]);
    if constexpr (SKIP) {
        const float* __restrict__ W25 = W1 + 25 * 32;
#pragma unroll
        for (int j = 0; j < 32; ++j) h[j] = fmaf(attr, W25[j], h[j]);
    }
    float out = b2[0];
#pragma unroll
    for (int j = 0; j < 32; ++j) out = fmaf(fmaxf(h[j], 0.0f), W2[j], out);

    if (valid) {
        if constexpr (STORE) e_out[i] = out;
        if constexpr (VALS) {
            const u32 eid = (u32)(key >> 34);
            vals_out[eid] = (r == c) ? expf(out) : out;
        }
    }
    if constexpr (GAGG) {
        const float s = wave_sum(valid ? out : 0.0f);
        if ((t & 63) == 0) wpart[t >> 6] = s;
        __syncthreads();
        if (t == 0)
            atomicAdd(&ebins[lid & 63],
                      wpart[0] + wpart[1] + wpart[2] + wpart[3]);
    }
}

// -- per-node MLP: CSR segment sum + MLP; EVEN also fuses the upper Atab --
// (l_n is in registers as o[8]; AtabU[n] = l_n . W1_next[8:16])

template <bool EVEN>
__global__ __launch_bounds__(256) void nodemlp_kernel(
    const float* __restrict__ ep,      // row-sorted edge embeddings
    const u32* __restrict__ row_offs,  // N+1 CSR offsets
    const float4* __restrict__ xf,   // node features: x (lower) or l_n (upper)
    const float* __restrict__ g,     // gslot[j] (materialized)
    const float* __restrict__ nW1, const float* __restrict__ nb1,
    const float* __restrict__ nW2, const float* __restrict__ nb2,
    float* __restrict__ n_out,         // l_n (8N) if EVEN
    float* __restrict__ nbins,         // 64 x 16 n-mean partial bins
    const float* __restrict__ W1u,     // next (upper) edge W1 slice, if EVEN
    float4* __restrict__ AtabU,        // upper A-table out, if EVEN
    int N, int cpn) {
    __shared__ float biasN[32];
    __shared__ float npart[4][8];
    const int t = threadIdx.x;
    if (t < 32) {
        float v = nb1[t];
#pragma unroll
        for (int k = 0; k < 8; ++k) v = fmaf(g[k], nW1[k * 32 + t], v);
        biasN[t] = v;
    }
    __syncthreads();
    const int lid = (blockIdx.x & 7) * cpn + (blockIdx.x >> 3);
    const int n = lid * 256 + t;
    const bool active = n < N;
    const int idx = active ? n : (N - 1);
    const u32 beg = row_offs[idx], end = row_offs[idx + 1];
    float ssum = 0.0f;
    for (u32 i = beg; i < end; ++i) ssum += ep[i];
    const float agg = ssum / fmaxf((float)(end - beg), 1.0f);
    const float4 x0 = xf[2 * (size_t)idx], x1 = xf[2 * (size_t)idx + 1];
    float in[9] = {x0.x, x0.y, x0.z, x0.w, x1.x, x1.y, x1.z, x1.w, agg};
    float h[32];
#pragma unroll
    for (int j = 0; j < 8; ++j) {
        const float4 bb = reinterpret_cast<const float4*>(biasN)[j];
        h[4 * j + 0] = bb.x; h[4 * j + 1] = bb.y;
        h[4 * j + 2] = bb.z; h[4 * j + 3] = bb.w;
    }
    const float* __restrict__ Wk = nW1 + 8 * 32;
#pragma unroll
    for (int k = 0; k < 9; ++k) {
        const float v = in[k];
#pragma unroll
        for (int j = 0; j < 32; ++j) h[j] = fmaf(v, Wk[k * 32 + j], h[j]);
    }
    float o[8];
#pragma unroll
    for (int q = 0; q < 8; ++q) o[q] = nb2[q];
#pragma unroll
    for (int j = 0; j < 32; ++j) {
        const float hv = fmaxf(h[j], 0.0f);
#pragma unroll
        for (int q = 0; q < 8; ++q) o[q] = fmaf(hv, nW2[j * 8 + q], o[q]);
    }
    if constexpr (EVEN) {
        if (active) {
            reinterpret_cast<float4*>(n_out)[2 * n] =
                make_float4(o[0], o[1], o[2], o[3]);
            reinterpret_cast<float4*>(n_out)[2 * n + 1] =
                make_float4(o[4], o[5], o[6], o[7]);
            // fused upper A-table: a = l_n . W1u[8:16]
            const float* __restrict__ WA = W1u + 8 * 32;
            float a[32];
#pragma unroll
            for (int j = 0; j < 32; ++j) a[j] = 0.0f;
#pragma unroll
            for (int k = 0; k < 8; ++k) {
                const float v = o[k];
#pragma unroll
                for (int j = 0; j < 32; ++j)
                    a[j] = fmaf(v, WA[k * 32 + j], a[j]);
            }
            float4* An = AtabU + 8 * (size_t)n;
#pragma unroll
            for (int q = 0; q < 8; ++q)
                An[q] = make_float4(a[4 * q], a[4 * q + 1], a[4 * q + 2],
                                    a[4 * q + 3]);
        }
    }
#pragma unroll
    for (int q = 0; q < 8; ++q) {
        const float s2 = wave_sum(active ? o[q] : 0.0f);
        if ((t & 63) == 0) npart[t >> 6][q] = s2;
    }
    __syncthreads();
    if (t < 8) {
        float a = 0.0f;
#pragma unroll
        for (int w = 0; w < 4; ++w) a += npart[w][t];
        atomicAdd(&nbins[(blockIdx.x & 63) * 16 + t], a);
    }
}

extern "C" void kernel_launch(void* const* d_in, const int* in_sizes, int n_in,
                              void* d_out, int out_size, void* d_ws,
                              size_t ws_size, hipStream_t stream) {
    const float* x = (const float*)d_in[0];
    const int* l_ei = (const int*)d_in[1];
    const int* u_ei = (const int*)d_in[2];
    const float* l_attr = (const float*)d_in[3];
    const float* u_attr = (const float*)d_in[4];
    const float* eW1 = (const float*)d_in[5];
    const float* eb1 = (const float*)d_in[6];
    const float* eW2 = (const float*)d_in[7];
    const float* eb2 = (const float*)d_in[8];
    const float* nW1 = (const float*)d_in[9];
    const float* nb1 = (const float*)d_in[10];
    const float* nW2 = (const float*)d_in[11];
    const float* nb2 = (const float*)d_in[12];
    const float* gW1 = (const float*)d_in[13];
    const float* gb1 = (const float*)d_in[14];
    const float* gW2 = (const float*)d_in[15];
    const float* gb2 = (const float*)d_in[16];

    const int E = in_sizes[3];      // 1,100,000
    const int N = in_sizes[0] / 8;  // 100,000
    const int B = (N + NB_SIZE - 1) >> NB_SHIFT;  // 391 buckets
    const int Ep = (E + 3) & ~3;    // float4-safe stride for emb arrays

    // workspace layout (~91MB, ws = 256MB):
    //  [ekeys 2E u64][eattrs 2E f32]
    //  [tmp (bucket order, E uint4; dead after sorts) -> AtabU(32N)+l_e(Ep)]
    //  [AtabL 96N (3 lower tables)][u_e Ep][l_n 8N][small region]
    u64* ekeys = (u64*)d_ws;                       // 2E keys
    float* eattrs = (float*)(ekeys + (size_t)2 * E);  // 2E attrs
    uint4* tmp = (uint4*)(eattrs + (size_t)2 * E); // E tmp records
    float* AtabU = (float*)tmp;                    // 32N (alias, post-sort)
    float* l_e = AtabU + (size_t)32 * N;           // Ep (alias, fits in tmp)
    float* AtabL = (float*)(tmp + (size_t)E);      // 96N (3 lower tables)
    float* u_e = AtabL + (size_t)96 * N;           // Ep
    float* l_n = u_e + Ep;                         // 8N
    float* gslot = l_n + (size_t)8 * N;            // 7 x 8
    u32* hist = (u32*)(gslot + 56);                // 2B
    float* dyn_all = (float*)(hist + 2 * B);       // 5 * RSTRIDE
    u32* offs = (u32*)(dyn_all + 5 * RSTRIDE);     // 2(B+1)
    u32* cur = offs + 2 * (B + 1);                 // 2B
    u32* row_offs = cur + 2 * B;                   // 2(N+1) CSR offsets

    const int* lr = l_ei;
    const int* lc = l_ei + E;
    const int* ur = u_ei;
    const int* uc = u_ei + E;
    const int sg = (E + SCHUNK - 1) / SCHUNK;
    const int ng = (N + 255) / 256;
    const int ngp = (ng + 7) & ~7;   // padded node grid (%8) for XCD swizzle
    const int cpn = ngp >> 3;
    const int eg = (E + 255) / 256;
    const int nwg8 = (eg + 7) & ~7;  // padded edge grid (%8)
    const int cpx = nwg8 >> 3;
    const float invE = 1.0f / (float)E;
    float* outL = (float*)d_out;
    float* outU = outL + E;

    // one memset: gslots + hist + all 5 bin regions
    hipMemsetAsync(gslot, 0, (size_t)(56 + 2 * B + 5 * RSTRIDE) * sizeof(float),
                   stream);
    hist_kernel<<<dim3(64, 2), 512, 0, stream>>>(lr, ur, hist, E, B);
    scan_kernel<<<1, 512, 0, stream>>>(hist, offs, cur, B);
    // per-segment scatter+sort, sequential (tmp holds ONE segment at a time)
    scatter_kernel<<<sg, 512, 0, stream>>>(lr, lc, l_attr, cur, tmp, E, B);
    sort_kernel<<<B, 512, 0, stream>>>(tmp, ekeys, eattrs, offs, row_offs,
                                       E, N);
    scatter_kernel<<<sg, 512, 0, stream>>>(ur, uc, u_attr, cur + B, tmp, E, B);
    sort_kernel<<<B, 512, 0, stream>>>(tmp, ekeys + (size_t)E,
                                       eattrs + (size_t)E, offs + (B + 1),
                                       row_offs + (N + 1), E, N);
    // all 3 lower A-tables (x is static; g now lives in edge biasE)
    atabx_kernel<<<ng, 256, 0, stream>>>((const float4*)x, eW1,
                                         (float4*)AtabL, N);

    // weight-slice per GraphNet j: lower i -> i, upper i -> 3+i
    const size_t wsl[6] = {0, 3, 1, 4, 2, 5};

    for (int j = 0; j < 6; ++j) {
        const bool lower = !(j & 1);
        const size_t sl = wsl[j];
        float* ebins = dyn_all + (size_t)(j <= 4 ? j : 4) * RSTRIDE;
        float* nbins = ebins + 64;
        const float* pe = (j >= 1) ? dyn_all + (size_t)(j - 1) * RSTRIDE : nullptr;
        const float* pn = (j >= 1) ? pe + 64 : nullptr;
        const size_t psl = (j >= 1) ? wsl[j - 1] : 0;
        const float4* exf = (const float4*)(lower ? x : l_n);
        const u64* ekey_t = ekeys + (size_t)(lower ? 0 : 1) * E;
        const float* eattr_t = eattrs + (size_t)(lower ? 0 : 1) * E;
        const u32* roffs = row_offs + (size_t)(lower ? 0 : 1) * (N + 1);
        const float* eprev = lower ? l_e : u_e;  // unused when FIRST
        float* e_out = lower ? l_e : u_e;
        const float* gprev = gslot + (size_t)(j >= 1 ? j - 1 : 0) * 8;
        float* gout = gslot + (size_t)j * 8;
        const float* Atab_j =
            lower ? AtabL + (size_t)(j >> 1) * 32 * N : AtabU;

#define EDGE_ARGS                                                             \
    ekey_t, eattr_t, (const float4*)Atab_j, exf, eprev, eW1 + sl * 832,       \
        eb1 + sl * 32, eW2 + sl * 32, eb2 + sl, gprev, gout, pe, pn,          \
        gW1 + psl * 544, gb1 + psl * 32, gW2 + psl * 256, gb2 + psl * 8,      \
        ebins, e_out, (j == 4) ? outL : outU, E, N, invE, cpx

        switch (j) {  // SKIP, FIRST, GAGG, VALS, STORE, GCOMP
            case 0: edge_kernel<false, true, true, false, true, false>
                        <<<nwg8, 256, 0, stream>>>(EDGE_ARGS); break;
            case 1: edge_kernel<false, true, true, false, true, true>
                        <<<nwg8, 256, 0, stream>>>(EDGE_ARGS); break;
            case 2: edge_kernel<true, false, true, false, true, true>
                        <<<nwg8, 256, 0, stream>>>(EDGE_ARGS); break;
            case 3: edge_kernel<false, false, true, false, true, true>
                        <<<nwg8, 256, 0, stream>>>(EDGE_ARGS); break;
            case 4: edge_kernel<true, false, true, true, true, true>
                        <<<nwg8, 256, 0, stream>>>(EDGE_ARGS); break;
            case 5: edge_kernel<false, false, false, true, false, true>
                        <<<nwg8, 256, 0, stream>>>(EDGE_ARGS); break;
        }
#undef EDGE_ARGS

        if (j == 5) break;  // final upper GraphNet: edge output only

#define NODE_ARGS                                                             \
    e_out, roffs, exf, gslot + (size_t)j * 8, nW1 + sl * 544, nb1 + sl * 32,  \
        nW2 + sl * 256, nb2 + sl * 8, l_n, nbins,                             \
        eW1 + wsl[j + 1] * 832, (float4*)AtabU, N, cpn

        switch (j) {  // EVEN (store l_n + fused upper Atab)
            case 0: nodemlp_kernel<true>
                        <<<ngp, 256, 0, stream>>>(NODE_ARGS); break;
            case 1: nodemlp_kernel<false>
                        <<<ngp, 256, 0, stream>>>(NODE_ARGS); break;
            case 2: nodemlp_kernel<true>
                        <<<ngp, 256, 0, stream>>>(NODE_ARGS); break;
            case 3: nodemlp_kernel<false>
                        <<<ngp, 256, 0, stream>>>(NODE_ARGS); break;
            case 4: nodemlp_kernel<true>
                        <<<ngp, 256, 0, stream>>>(NODE_ARGS); break;
        }
#undef NODE_ARGS
    }
}

// Round 13
// 489.874 us; speedup vs baseline: 1.1302x; 1.0281x over previous
//
#include <hip/hip_runtime.h>

// NeuralIF GraphNet: 3 layers x (lower GraphNet, upper GraphNet).
// R7: one-edge-per-thread edge kernel. 548us.
// R8 FAILED: global A/B tables, original edge order -> 139MB L3 gather.
// R9: bucket-permuted order; scatter write-amp -> 120us.
// R10 FAILED: per-bucket edge blocks w/ 64KB LDS window -> occupancy 20%.
// R11: flat one-edge-per-thread, 256-node buckets, folded Atab. 549us.
// R12 FAILED: fused aggregation via global nsum[row] atomics.
// R14: full row sort + CSR nodemlp + seq per-segment scatter/sort. 508.9us.
// R15: u64 key + split attr. NEUTRAL -> not stream-BW-bound.
// R16/R18 FAILED-BY-SPILL x2: 2 edges/thread spills h[32] pair. Abandoned.
// R17: XCD swizzle on nodew/nodemlp. NEUTRAL.
// R19: nodew dispatches eliminated (atabx upfront x3 lower tables; upper
//      Atab fused into even nodemlp; g folded in edge biasE). 503.6us BEST.
//      Learned: ws_size = 256MB (poison fills) -> R13's "OOB" theory wrong;
//      its container fault was infra. Profile's 31.9ms nodemlp row = rocprof
//      replay artifact (stale row_offs); timed total proves it unreal.
// R20 (this round): dispatch-fill + gap elimination. Launch-gap budget is
//      ~100us (18 dispatches x ~5.5us). Per-segment scatter (269 blk) and
//      sort (391 blk) fill ~1 blk/CU -> machine half-empty, twice, serially.
//      Merge to dual-segment single dispatches (blockIdx.y = segment, the
//      R9-R12-proven shape): 538/782 blocks, -2 dispatches, serial 2x -> 1.1x.
//      tmp grows to 2E (35.2MB); dead tmp absorbs AtabU+l_e+u_e+l_n (24.8MB).

typedef unsigned int u32;
typedef unsigned long long u64;

#define NB_SHIFT 8
#define NB_SIZE 256
#define RSTRIDE 1104  // per-GraphNet region: ebins[64] nbins[64*16] pad

__device__ __forceinline__ float wave_sum(float v) {
#pragma unroll
    for (int off = 32; off > 0; off >>= 1) v += __shfl_down(v, off, 64);
    return v;
}

// ---------------- bucketed-list build (once per call) ----------------

__global__ __launch_bounds__(512) void hist_kernel(
    const int* __restrict__ lr, const int* __restrict__ ur,
    u32* __restrict__ hist, int E, int B) {
    __shared__ u32 h[512];
    const int t = threadIdx.x;
    if (t < B) h[t] = 0;
    __syncthreads();
    const int s = blockIdx.y;
    const int* rows = s ? ur : lr;
    for (int i = blockIdx.x * 512 + t; i < E; i += gridDim.x * 512)
        atomicAdd(&h[rows[i] >> NB_SHIFT], 1u);
    __syncthreads();
    if (t < B && h[t]) atomicAdd(&hist[s * B + t], h[t]);
}

// parallel exclusive scan of both segments (B <= 512), one block
__global__ __launch_bounds__(512) void scan_kernel(
    const u32* __restrict__ hist, u32* __restrict__ offs,
    u32* __restrict__ cur, int B) {
    __shared__ u32 sh[512];
    const int t = threadIdx.x;
    for (int s = 0; s < 2; ++s) {
        const u32 v = (t < B) ? hist[s * B + t] : 0u;
        sh[t] = v;
        __syncthreads();
#pragma unroll
        for (int off = 1; off < 512; off <<= 1) {
            const u32 add = (t >= off) ? sh[t - off] : 0u;
            __syncthreads();
            sh[t] += add;
            __syncthreads();
        }
        const u32 exc = sh[t] - v;
        if (t < B) {
            offs[s * (B + 1) + t] = exc;
            cur[s * B + t] = exc;
        }
        if (t == 511) offs[s * (B + 1) + B] = sh[511];
        __syncthreads();
    }
}

// dual-segment scatter: packed bucket-permuted records {row, col, eid, attr}
#define SCHUNK 4096
__global__ __launch_bounds__(512) void scatter_kernel(
    const int* __restrict__ lr, const int* __restrict__ lc,
    const int* __restrict__ ur, const int* __restrict__ uc,
    const float* __restrict__ la, const float* __restrict__ ua,
    u32* __restrict__ cur, uint4* __restrict__ tmp, int E, int B) {
    __shared__ u32 lcnt[512], lbase[512];
    const int t = threadIdx.x;
    const int s = blockIdx.y;
    const int* rows = s ? ur : lr;
    const int* cols = s ? uc : lc;
    const float* attr = s ? ua : la;
    uint4* my = tmp + (size_t)s * E;
    if (t < B) lcnt[t] = 0;
    __syncthreads();
    const int base_e = blockIdx.x * SCHUNK;
#pragma unroll
    for (int k = 0; k < SCHUNK / 512; ++k) {
        const int e = base_e + k * 512 + t;
        if (e < E) atomicAdd(&lcnt[rows[e] >> NB_SHIFT], 1u);
    }
    __syncthreads();
    if (t < B) {
        const u32 c = lcnt[t];
        lbase[t] = c ? atomicAdd(&cur[s * B + t], c) : 0u;
        lcnt[t] = 0;
    }
    __syncthreads();
#pragma unroll
    for (int k = 0; k < SCHUNK / 512; ++k) {
        const int e = base_e + k * 512 + t;
        if (e < E) {
            const int r = rows[e];
            const int b = r >> NB_SHIFT;
            const u32 pos = lbase[b] + atomicAdd(&lcnt[b], 1u);
            my[pos] = make_uint4((u32)r, (u32)cols[e], (u32)e,
                                 __float_as_uint(attr[e]));
        }
    }
}

// ---- dual-segment per-bucket LDS counting sort: bucket -> row order ----
// Emits split arrays: u64 key {eid:21|row:17|col:17} + float attr.
// Also emits per-node CSR offsets (row_offs). One block per (bucket,segment).

__global__ __launch_bounds__(512) void sort_kernel(
    const uint4* __restrict__ tmp, u64* __restrict__ ekeys,
    float* __restrict__ eattrs, const u32* __restrict__ offs,
    u32* __restrict__ row_offs, int E, int N, int B) {
    __shared__ u32 cnt[NB_SIZE];
    __shared__ u32 scn[NB_SIZE];
    const int t = threadIdx.x;
    const int s = blockIdx.y;
    const int b = blockIdx.x;
    const uint4* in = tmp + (size_t)s * E;
    u64* okey = ekeys + (size_t)s * E;
    float* oattr = eattrs + (size_t)s * E;
    u32* rofs = row_offs + (size_t)s * (N + 1);
    const u32 beg = offs[s * (B + 1) + b], end = offs[s * (B + 1) + b + 1];
    if (t < NB_SIZE) cnt[t] = 0;
    __syncthreads();
    for (u32 i = beg + t; i < end; i += 512)
        atomicAdd(&cnt[in[i].x & (NB_SIZE - 1)], 1u);
    __syncthreads();
    if (t < NB_SIZE) scn[t] = cnt[t];
    __syncthreads();
#pragma unroll
    for (int off = 1; off < NB_SIZE; off <<= 1) {
        u32 add = 0;
        if (t < NB_SIZE && t >= off) add = scn[t - off];
        __syncthreads();
        if (t < NB_SIZE) scn[t] += add;
        __syncthreads();
    }
    const int n0 = b << NB_SHIFT;
    if (t < NB_SIZE) {
        const u32 excl = scn[t] - cnt[t];
        if (n0 + t < N) rofs[n0 + t] = beg + excl;
        cnt[t] = excl;  // reuse as write cursor
    }
    if (b == 0 && t == 0) rofs[N] = (u32)E;
    __syncthreads();
    for (u32 i = beg + t; i < end; i += 512) {
        const uint4 r = in[i];
        const u32 pos = beg + atomicAdd(&cnt[r.x & (NB_SIZE - 1)], 1u);
        okey[pos] = ((u64)r.z << 34) | ((u64)(r.x & 0x1FFFFu) << 17) |
                    (u64)(r.y & 0x1FFFFu);
        oattr[pos] = __uint_as_float(r.w);
    }
}

// ---- upfront: all 3 lower A-tables from static x (g-independent) ----
// AtabL[m][n][j] = sum_k x[n,k] * W1_m[(8+k)*32+j], m = lower slice 0,1,2

__global__ __launch_bounds__(256) void atabx_kernel(
    const float4* __restrict__ xf, const float* __restrict__ eW1,
    float4* __restrict__ AtabL, int N) {
    const int n = blockIdx.x * 256 + threadIdx.x;
    if (n >= N) return;
    const float4 x0 = xf[2 * (size_t)n], x1 = xf[2 * (size_t)n + 1];
    const float xs[8] = {x0.x, x0.y, x0.z, x0.w, x1.x, x1.y, x1.z, x1.w};
    for (int m = 0; m < 3; ++m) {
        const float* __restrict__ WA = eW1 + (size_t)m * 832 + 8 * 32;
        float a[32];
#pragma unroll
        for (int j = 0; j < 32; ++j) a[j] = 0.0f;
#pragma unroll
        for (int k = 0; k < 8; ++k) {
            const float v = xs[k];
#pragma unroll
            for (int j = 0; j < 32; ++j) a[j] = fmaf(v, WA[k * 32 + j], a[j]);
        }
        float4* An = AtabL + (size_t)m * 8 * N + 8 * (size_t)n;
#pragma unroll
        for (int q = 0; q < 8; ++q)
            An[q] = make_float4(a[4 * q], a[4 * q + 1], a[4 * q + 2],
                                a[4 * q + 3]);
    }
}

// ---------------- edge MLP: flat grid, one edge per thread ----------------
// GCOMP (wave 0) computes g inline from prev bins; t<32 folds b1 + g.W1[0:8]
// into LDS biasE. Atab rows carry only x.W1[8:16]. Row-sorted order keeps
// A-row gathers L1-broadcast; XCD-chunked swizzle.

template <bool SKIP, bool FIRST, bool GAGG, bool VALS, bool STORE, bool GCOMP>
__global__ __launch_bounds__(256) void edge_kernel(
    const u64* __restrict__ ekey,      // packed row-sorted keys
    const float* __restrict__ eattr,   // permuted original attrs
    const float4* __restrict__ Atab,   // per-node x.W1[8:16] partials
    const float4* __restrict__ xf,     // current node features (x or l_n)
    const float* __restrict__ eprev,   // prev edge emb (permuted), !FIRST
    const float* __restrict__ W1,      // 26x32 slice (row-major k,j)
    const float* __restrict__ b1,      // 32
    const float* __restrict__ W2,      // 32
    const float* __restrict__ b2,      // 1
    const float* __restrict__ gprev,   // gslot[j-1] (or gslot[0]=0)
    float* __restrict__ gout,          // gslot[j] (GCOMP: block0 writes)
    const float* __restrict__ pebins,  // prev region e-mean bins (GCOMP)
    const float* __restrict__ pnbins,  // prev region n-mean bins (GCOMP)
    const float* __restrict__ gW1, const float* __restrict__ gb1,
    const float* __restrict__ gW2, const float* __restrict__ gb2,
    float* __restrict__ ebins,         // this region's e-mean bins (GAGG)
    float* __restrict__ e_out,         // edge emb store (permuted, STORE)
    float* __restrict__ vals_out,      // final output segment (VALS)
    int E, int N, float inv_E, int cpx) {
    __shared__ float gsh[8];
    __shared__ float biasE[32];
    __shared__ float wpart[4];
    const int t = threadIdx.x;
    const int lid = (blockIdx.x & 7) * cpx + (blockIdx.x >> 3);
    const int i0 = lid * 256;
    if (i0 >= E) return;  // padded-grid tail block (uniform exit)

    if constexpr (GCOMP) {
        if (t < 64) {  // wave 0: g = gMLP(n_mean, e_mean, g_prev)
            float nb[8];
#pragma unroll
            for (int q = 0; q < 8; ++q) nb[q] = pnbins[t * 16 + q];
            const float eb = pebins[t];
            float gin[17];
#pragma unroll
            for (int q = 0; q < 8; ++q) {
                const float s = wave_sum(nb[q]);
                gin[q] = __shfl(s, 0, 64) / (float)N;
            }
            const float es = wave_sum(eb);
            gin[8] = __shfl(es, 0, 64) * inv_E;
#pragma unroll
            for (int k = 0; k < 8; ++k) gin[9 + k] = gprev[k];
            float hv = 0.0f;
            if (t < 32) {
                hv = gb1[t];
#pragma unroll
                for (int k = 0; k < 17; ++k)
                    hv = fmaf(gin[k], gW1[k * 32 + t], hv);
                hv = fmaxf(hv, 0.0f);
            }
#pragma unroll
            for (int q = 0; q < 8; ++q) {
                const float c = (t < 32) ? hv * gW2[t * 8 + q] : 0.0f;
                const float s = wave_sum(c);
                if (t == 0) {
                    const float gv = gb2[q] + s;
                    gsh[q] = gv;
                    if (blockIdx.x == 0) gout[q] = gv;
                }
            }
        }
    } else {
        if (t < 8) gsh[t] = gprev[t];  // zeros for GraphNet 0
    }
    __syncthreads();
    if (t < 32) {  // fold uniform global contribution + b1 into bias
        float v = b1[t];
#pragma unroll
        for (int k = 0; k < 8; ++k) v = fmaf(gsh[k], W1[k * 32 + t], v);
        biasE[t] = v;
    }
    __syncthreads();

    const int i = i0 + t;
    const bool valid = i < E;
    const int idx = valid ? i : i0;

    const u64 key = ekey[idx];
    const u32 c = (u32)key & 0x1FFFFu;
    const u32 r = (u32)(key >> 17) & 0x1FFFFu;
    float attr = 0.0f;
    if constexpr (FIRST || SKIP) attr = eattr[idx];
    float epv;
    if constexpr (FIRST) epv = attr;
    else epv = eprev[idx];
    // A-row gather (8x16B; consecutive lanes share rows -> broadcast)
    const float4* __restrict__ Ar = Atab + 8 * (size_t)r;
    float h[32];
#pragma unroll
    for (int q = 0; q < 8; ++q) {
        const float4 av = Ar[q];
        const float4 bi = reinterpret_cast<const float4*>(biasE)[q];
        h[4 * q + 0] = bi.x + av.x; h[4 * q + 1] = bi.y + av.y;
        h[4 * q + 2] = bi.z + av.z; h[4 * q + 3] = bi.w + av.w;
    }
    // col features (32B gather, L2-resident table)
    const float4 xc0 = xf[2 * (size_t)c], xc1 = xf[2 * (size_t)c + 1];
    const float cx[8] = {xc0.x, xc0.y, xc0.z, xc0.w,
                         xc1.x, xc1.y, xc1.z, xc1.w};
    const float* __restrict__ Wc = W1 + 16 * 32;  // col rows 16..23
#pragma unroll
    for (int k = 0; k < 8; ++k) {
        const float v = cx[k];
#pragma unroll
        for (int j = 0; j < 32; ++j) h[j] = fmaf(v, Wc[k * 32 + j], h[j]);
    }
    const float* __restrict__ W24 = W1 + 24 * 32;
#pragma unroll
    for (int j = 0; j < 32; ++j) h[j] = fmaf(epv, W24[j], h[j]);
    if constexpr (SKIP) {
        const float* __restrict__ W25 = W1 + 25 * 32;
#pragma unroll
        for (int j = 0; j < 32; ++j) h[j] = fmaf(attr, W25[j], h[j]);
    }
    float out = b2[0];
#pragma unroll
    for (int j = 0; j < 32; ++j) out = fmaf(fmaxf(h[j], 0.0f), W2[j], out);

    if (valid) {
        if constexpr (STORE) e_out[i] = out;
        if constexpr (VALS) {
            const u32 eid = (u32)(key >> 34);
            vals_out[eid] = (r == c) ? expf(out) : out;
        }
    }
    if constexpr (GAGG) {
        const float s = wave_sum(valid ? out : 0.0f);
        if ((t & 63) == 0) wpart[t >> 6] = s;
        __syncthreads();
        if (t == 0)
            atomicAdd(&ebins[lid & 63],
                      wpart[0] + wpart[1] + wpart[2] + wpart[3]);
    }
}

// -- per-node MLP: CSR segment sum + MLP; EVEN also fuses the upper Atab --
// (l_n is in registers as o[8]; AtabU[n] = l_n . W1_next[8:16])

template <bool EVEN>
__global__ __launch_bounds__(256) void nodemlp_kernel(
    const float* __restrict__ ep,      // row-sorted edge embeddings
    const u32* __restrict__ row_offs,  // N+1 CSR offsets
    const float4* __restrict__ xf,   // node features: x (lower) or l_n (upper)
    const float* __restrict__ g,     // gslot[j] (materialized)
    const float* __restrict__ nW1, const float* __restrict__ nb1,
    const float* __restrict__ nW2, const float* __restrict__ nb2,
    float* __restrict__ n_out,         // l_n (8N) if EVEN
    float* __restrict__ nbins,         // 64 x 16 n-mean partial bins
    const float* __restrict__ W1u,     // next (upper) edge W1 slice, if EVEN
    float4* __restrict__ AtabU,        // upper A-table out, if EVEN
    int N, int cpn) {
    __shared__ float biasN[32];
    __shared__ float npart[4][8];
    const int t = threadIdx.x;
    if (t < 32) {
        float v = nb1[t];
#pragma unroll
        for (int k = 0; k < 8; ++k) v = fmaf(g[k], nW1[k * 32 + t], v);
        biasN[t] = v;
    }
    __syncthreads();
    const int lid = (blockIdx.x & 7) * cpn + (blockIdx.x >> 3);
    const int n = lid * 256 + t;
    const bool active = n < N;
    const int idx = active ? n : (N - 1);
    const u32 beg = row_offs[idx], end = row_offs[idx + 1];
    float ssum = 0.0f;
    for (u32 i = beg; i < end; ++i) ssum += ep[i];
    const float agg = ssum / fmaxf((float)(end - beg), 1.0f);
    const float4 x0 = xf[2 * (size_t)idx], x1 = xf[2 * (size_t)idx + 1];
    float in[9] = {x0.x, x0.y, x0.z, x0.w, x1.x, x1.y, x1.z, x1.w, agg};
    float h[32];
#pragma unroll
    for (int j = 0; j < 8; ++j) {
        const float4 bb = reinterpret_cast<const float4*>(biasN)[j];
        h[4 * j + 0] = bb.x; h[4 * j + 1] = bb.y;
        h[4 * j + 2] = bb.z; h[4 * j + 3] = bb.w;
    }
    const float* __restrict__ Wk = nW1 + 8 * 32;
#pragma unroll
    for (int k = 0; k < 9; ++k) {
        const float v = in[k];
#pragma unroll
        for (int j = 0; j < 32; ++j) h[j] = fmaf(v, Wk[k * 32 + j], h[j]);
    }
    float o[8];
#pragma unroll
    for (int q = 0; q < 8; ++q) o[q] = nb2[q];
#pragma unroll
    for (int j = 0; j < 32; ++j) {
        const float hv = fmaxf(h[j], 0.0f);
#pragma unroll
        for (int q = 0; q < 8; ++q) o[q] = fmaf(hv, nW2[j * 8 + q], o[q]);
    }
    if constexpr (EVEN) {
        if (active) {
            reinterpret_cast<float4*>(n_out)[2 * n] =
                make_float4(o[0], o[1], o[2], o[3]);
            reinterpret_cast<float4*>(n_out)[2 * n + 1] =
                make_float4(o[4], o[5], o[6], o[7]);
            // fused upper A-table: a = l_n . W1u[8:16]
            const float* __restrict__ WA = W1u + 8 * 32;
            float a[32];
#pragma unroll
            for (int j = 0; j < 32; ++j) a[j] = 0.0f;
#pragma unroll
            for (int k = 0; k < 8; ++k) {
                const float v = o[k];
#pragma unroll
                for (int j = 0; j < 32; ++j)
                    a[j] = fmaf(v, WA[k * 32 + j], a[j]);
            }
            float4* An = AtabU + 8 * (size_t)n;
#pragma unroll
            for (int q = 0; q < 8; ++q)
                An[q] = make_float4(a[4 * q], a[4 * q + 1], a[4 * q + 2],
                                    a[4 * q + 3]);
        }
    }
#pragma unroll
    for (int q = 0; q < 8; ++q) {
        const float s2 = wave_sum(active ? o[q] : 0.0f);
        if ((t & 63) == 0) npart[t >> 6][q] = s2;
    }
    __syncthreads();
    if (t < 8) {
        float a = 0.0f;
#pragma unroll
        for (int w = 0; w < 4; ++w) a += npart[w][t];
        atomicAdd(&nbins[(blockIdx.x & 63) * 16 + t], a);
    }
}

extern "C" void kernel_launch(void* const* d_in, const int* in_sizes, int n_in,
                              void* d_out, int out_size, void* d_ws,
                              size_t ws_size, hipStream_t stream) {
    const float* x = (const float*)d_in[0];
    const int* l_ei = (const int*)d_in[1];
    const int* u_ei = (const int*)d_in[2];
    const float* l_attr = (const float*)d_in[3];
    const float* u_attr = (const float*)d_in[4];
    const float* eW1 = (const float*)d_in[5];
    const float* eb1 = (const float*)d_in[6];
    const float* eW2 = (const float*)d_in[7];
    const float* eb2 = (const float*)d_in[8];
    const float* nW1 = (const float*)d_in[9];
    const float* nb1 = (const float*)d_in[10];
    const float* nW2 = (const float*)d_in[11];
    const float* nb2 = (const float*)d_in[12];
    const float* gW1 = (const float*)d_in[13];
    const float* gb1 = (const float*)d_in[14];
    const float* gW2 = (const float*)d_in[15];
    const float* gb2 = (const float*)d_in[16];

    const int E = in_sizes[3];      // 1,100,000
    const int N = in_sizes[0] / 8;  // 100,000
    const int B = (N + NB_SIZE - 1) >> NB_SHIFT;  // 391 buckets
    const int Ep = (E + 3) & ~3;    // float4-safe stride for emb arrays

    // workspace layout (~101MB, ws = 256MB):
    //  [ekeys 2E u64 17.6][eattrs 2E f32 8.8]
    //  [tmp 2E uint4 35.2 (dead after sort) -> AtabU 12.8 + l_e + u_e + l_n]
    //  [AtabL 96N 38.4][small region]
    u64* ekeys = (u64*)d_ws;                       // 2E keys
    float* eattrs = (float*)(ekeys + (size_t)2 * E);  // 2E attrs
    uint4* tmp = (uint4*)(eattrs + (size_t)2 * E); // 2E tmp records
    float* AtabU = (float*)tmp;                    // 32N (alias, post-sort)
    float* l_e = AtabU + (size_t)32 * N;           // Ep (alias)
    float* u_e = l_e + Ep;                         // Ep (alias)
    float* l_n = u_e + Ep;                         // 8N (alias; fits in tmp)
    float* AtabL = (float*)(tmp + (size_t)2 * E);  // 96N (3 lower tables)
    float* gslot = AtabL + (size_t)96 * N;         // 7 x 8
    u32* hist = (u32*)(gslot + 56);                // 2B
    float* dyn_all = (float*)(hist + 2 * B);       // 5 * RSTRIDE
    u32* offs = (u32*)(dyn_all + 5 * RSTRIDE);     // 2(B+1)
    u32* cur = offs + 2 * (B + 1);                 // 2B
    u32* row_offs = cur + 2 * B;                   // 2(N+1) CSR offsets

    const int* lr = l_ei;
    const int* lc = l_ei + E;
    const int* ur = u_ei;
    const int* uc = u_ei + E;
    const int sg = (E + SCHUNK - 1) / SCHUNK;
    const int ng = (N + 255) / 256;
    const int ngp = (ng + 7) & ~7;   // padded node grid (%8) for XCD swizzle
    const int cpn = ngp >> 3;
    const int eg = (E + 255) / 256;
    const int nwg8 = (eg + 7) & ~7;  // padded edge grid (%8)
    const int cpx = nwg8 >> 3;
    const float invE = 1.0f / (float)E;
    float* outL = (float*)d_out;
    float* outU = outL + E;

    // one memset: gslots + hist + all 5 bin regions
    hipMemsetAsync(gslot, 0, (size_t)(56 + 2 * B + 5 * RSTRIDE) * sizeof(float),
                   stream);
    hist_kernel<<<dim3(64, 2), 512, 0, stream>>>(lr, ur, hist, E, B);
    scan_kernel<<<1, 512, 0, stream>>>(hist, offs, cur, B);
    // dual-segment scatter + sort (blockIdx.y = segment): full machine fill
    scatter_kernel<<<dim3(sg, 2), 512, 0, stream>>>(lr, lc, ur, uc, l_attr,
                                                    u_attr, cur, tmp, E, B);
    sort_kernel<<<dim3(B, 2), 512, 0, stream>>>(tmp, ekeys, eattrs, offs,
                                                row_offs, E, N, B);
    // all 3 lower A-tables (x is static; g lives in edge biasE)
    atabx_kernel<<<ng, 256, 0, stream>>>((const float4*)x, eW1,
                                         (float4*)AtabL, N);

    // weight-slice per GraphNet j: lower i -> i, upper i -> 3+i
    const size_t wsl[6] = {0, 3, 1, 4, 2, 5};

    for (int j = 0; j < 6; ++j) {
        const bool lower = !(j & 1);
        const size_t sl = wsl[j];
        float* ebins = dyn_all + (size_t)(j <= 4 ? j : 4) * RSTRIDE;
        float* nbins = ebins + 64;
        const float* pe = (j >= 1) ? dyn_all + (size_t)(j - 1) * RSTRIDE : nullptr;
        const float* pn = (j >= 1) ? pe + 64 : nullptr;
        const size_t psl = (j >= 1) ? wsl[j - 1] : 0;
        const float4* exf = (const float4*)(lower ? x : l_n);
        const u64* ekey_t = ekeys + (size_t)(lower ? 0 : 1) * E;
        const float* eattr_t = eattrs + (size_t)(lower ? 0 : 1) * E;
        const u32* roffs = row_offs + (size_t)(lower ? 0 : 1) * (N + 1);
        const float* eprev = lower ? l_e : u_e;  // unused when FIRST
        float* e_out = lower ? l_e : u_e;
        const float* gprev = gslot + (size_t)(j >= 1 ? j - 1 : 0) * 8;
        float* gout = gslot + (size_t)j * 8;
        const float* Atab_j =
            lower ? AtabL + (size_t)(j >> 1) * 32 * N : AtabU;

#define EDGE_ARGS                                                             \
    ekey_t, eattr_t, (const float4*)Atab_j, exf, eprev, eW1 + sl * 832,       \
        eb1 + sl * 32, eW2 + sl * 32, eb2 + sl, gprev, gout, pe, pn,          \
        gW1 + psl * 544, gb1 + psl * 32, gW2 + psl * 256, gb2 + psl * 8,      \
        ebins, e_out, (j == 4) ? outL : outU, E, N, invE, cpx

        switch (j) {  // SKIP, FIRST, GAGG, VALS, STORE, GCOMP
            case 0: edge_kernel<false, true, true, false, true, false>
                        <<<nwg8, 256, 0, stream>>>(EDGE_ARGS); break;
            case 1: edge_kernel<false, true, true, false, true, true>
                        <<<nwg8, 256, 0, stream>>>(EDGE_ARGS); break;
            case 2: edge_kernel<true, false, true, false, true, true>
                        <<<nwg8, 256, 0, stream>>>(EDGE_ARGS); break;
            case 3: edge_kernel<false, false, true, false, true, true>
                        <<<nwg8, 256, 0, stream>>>(EDGE_ARGS); break;
            case 4: edge_kernel<true, false, true, true, true, true>
                        <<<nwg8, 256, 0, stream>>>(EDGE_ARGS); break;
            case 5: edge_kernel<false, false, false, true, false, true>
                        <<<nwg8, 256, 0, stream>>>(EDGE_ARGS); break;
        }
#undef EDGE_ARGS

        if (j == 5) break;  // final upper GraphNet: edge output only

#define NODE_ARGS                                                             \
    e_out, roffs, exf, gslot + (size_t)j * 8, nW1 + sl * 544, nb1 + sl * 32,  \
        nW2 + sl * 256, nb2 + sl * 8, l_n, nbins,                             \
        eW1 + wsl[j + 1] * 832, (float4*)AtabU, N, cpn

        switch (j) {  // EVEN (store l_n + fused upper Atab)
            case 0: nodemlp_kernel<true>
                        <<<ngp, 256, 0, stream>>>(NODE_ARGS); break;
            case 1: nodemlp_kernel<false>
                        <<<ngp, 256, 0, stream>>>(NODE_ARGS); break;
            case 2: nodemlp_kernel<true>
                        <<<ngp, 256, 0, stream>>>(NODE_ARGS); break;
            case 3: nodemlp_kernel<false>
                        <<<ngp, 256, 0, stream>>>(NODE_ARGS); break;
            case 4: nodemlp_kernel<true>
                        <<<ngp, 256, 0, stream>>>(NODE_ARGS); break;
        }
#undef NODE_ARGS
    }
}